// Round 4
// baseline (351.136 us; speedup 1.0000x reference)
//
#include <hip/hip_runtime.h>
#include <hip/hip_bf16.h>

typedef __attribute__((ext_vector_type(8))) short short8;
typedef __attribute__((ext_vector_type(4))) short s16x4;
typedef __attribute__((ext_vector_type(4))) float f32x4;

__device__ inline short f2bf(float f) {
    union { float f; unsigned u; } v; v.f = f;
    unsigned r = v.u + 0x7fffu + ((v.u >> 16) & 1u);
    return (short)(r >> 16);
}
__device__ inline short f2h(float f) {
    union { _Float16 h; short s; } u; u.h = (_Float16)f; return u.s;
}
__device__ inline float h2f(short s) {
    union { short s; _Float16 h; } u; u.s = s; return (float)u.h;
}

// ---------------------------------------------------------------------------
// K1: qkv = x @ W_qkv   (M=8192, K=512, N=1536), scatter to
//     q[b*8+h][n][d] bf16 (pre-scaled by DH^-0.5), k[..] bf16, vT[bh][d][n]
// ---------------------------------------------------------------------------
__global__ __launch_bounds__(256) void qkv_gemm(
    const float* __restrict__ x, const float* __restrict__ W,
    short* __restrict__ q, short* __restrict__ k, short* __restrict__ vt)
{
    __shared__ short sA[64][40];
    __shared__ short sBt[64][40];

    const int tid  = threadIdx.x;
    const int wv   = tid >> 6, lane = tid & 63;
    const int quad = lane >> 4, l16 = lane & 15;
    const int m0 = blockIdx.x * 64, n0 = blockIdx.y * 64;

    f32x4 acc[4];
#pragma unroll
    for (int i = 0; i < 4; i++) acc[i] = (f32x4){0.f, 0.f, 0.f, 0.f};

    const int ar = tid >> 2, ac = (tid & 3) * 8;
    const int bk = tid >> 3, bn = (tid & 7) * 8;

    for (int ks = 0; ks < 16; ks++) {
        const int k0 = ks * 32;
        const float* xp = x + (size_t)(m0 + ar) * 512 + k0 + ac;
        float4 a0 = *(const float4*)xp;
        float4 a1 = *(const float4*)(xp + 4);
        const float* wp = W + (size_t)(k0 + bk) * 1536 + n0 + bn;
        float4 b0 = *(const float4*)wp;
        float4 b1 = *(const float4*)(wp + 4);

        __syncthreads();
        short8 av = { f2bf(a0.x), f2bf(a0.y), f2bf(a0.z), f2bf(a0.w),
                      f2bf(a1.x), f2bf(a1.y), f2bf(a1.z), f2bf(a1.w) };
        *(short8*)&sA[ar][ac] = av;
        sBt[bn + 0][bk] = f2bf(b0.x); sBt[bn + 1][bk] = f2bf(b0.y);
        sBt[bn + 2][bk] = f2bf(b0.z); sBt[bn + 3][bk] = f2bf(b0.w);
        sBt[bn + 4][bk] = f2bf(b1.x); sBt[bn + 5][bk] = f2bf(b1.y);
        sBt[bn + 6][bk] = f2bf(b1.z); sBt[bn + 7][bk] = f2bf(b1.w);
        __syncthreads();

        short8 af = *(const short8*)&sA[wv * 16 + l16][quad * 8];
#pragma unroll
        for (int ns = 0; ns < 4; ns++) {
            short8 bf = *(const short8*)&sBt[ns * 16 + l16][quad * 8];
            acc[ns] = __builtin_amdgcn_mfma_f32_16x16x32_bf16(af, bf, acc[ns], 0, 0, 0);
        }
    }

#pragma unroll
    for (int ns = 0; ns < 4; ns++) {
        const int gc  = n0 + ns * 16 + l16;
        const int sec = gc >> 9;          // 0=q 1=k 2=v
        const int cc  = gc & 511;
        const int h = cc >> 6, d = cc & 63;
#pragma unroll
        for (int i = 0; i < 4; i++) {
            const int gm = m0 + wv * 16 + quad * 4 + i;
            const int b = gm >> 10, n = gm & 1023;
            const int bh = b * 8 + h;
            if (sec == 0)      q[((size_t)(bh * 1024 + n)) * 64 + d] = f2bf(acc[ns][i] * 0.125f);
            else if (sec == 1) k[((size_t)(bh * 1024 + n)) * 64 + d] = f2bf(acc[ns][i]);
            else               vt[((size_t)(bh * 64 + d)) * 1024 + n] = f2bf(acc[ns][i]);
        }
    }
}

// ---------------------------------------------------------------------------
// K2: attention. One block = one (b,h) x 16 query rows. 4 waves x 256 cols.
// Score stripe in 64 acc VGPRs/lane (ALL acc loops fully unrolled — runtime
// index demotes to scratch, R1 lesson). spd stripe staged ONCE to LDS (fp16)
// via coalesced float4 loads; passes read it from LDS. sP buffer is reused:
// sv (fp16 spd) during passes 1-2, P (bf16) for the PV phase.
// ---------------------------------------------------------------------------
__global__ __launch_bounds__(256) void attn_k(
    const short* __restrict__ q, const short* __restrict__ kk,
    const short* __restrict__ vt, const float* __restrict__ spd,
    const float* __restrict__ hm, short* __restrict__ o)
{
    __shared__ short sP[16][1032];     // 33 KB: fp16 spd, then bf16 P
    __shared__ float sred[2][4][16];
    __shared__ float ratio_s[16], rmax_s[16], rinv_s[16];

    const int tid  = threadIdx.x;
    const int wv   = tid >> 6, lane = tid & 63;
    const int quad = lane >> 4, l16 = lane & 15;
    const int qt = blockIdx.x, bh = blockIdx.y;
    const int b = bh >> 3, h = bh & 7;
    const int q0 = qt * 16;

    // ---- stage spd stripe -> LDS fp16 (coalesced float4, 4KB/instr) ----
    const float* spdb = spd + ((size_t)b * 1024 + q0) * 1024;
#pragma unroll
    for (int it = 0; it < 16; it++) {
        float4 v = *(const float4*)(spdb + (size_t)it * 1024 + tid * 4);
        s16x4 hh = { f2h(v.x), f2h(v.y), f2h(v.z), f2h(v.w) };
        *(s16x4*)&sP[it][tid * 4] = hh;
    }

    // Q fragments (A-layout): m = l16, k = quad*8+j (+32 for second step)
    const short* qb = q + ((size_t)bh * 1024 + q0 + l16) * 64;
    short8 aq0 = *(const short8*)(qb + quad * 8);
    short8 aq1 = *(const short8*)(qb + 32 + quad * 8);

    f32x4 acc[16];
#pragma unroll
    for (int t = 0; t < 16; t++) acc[t] = (f32x4){0.f, 0.f, 0.f, 0.f};

    const short* kbh = kk + (size_t)bh * 1024 * 64;
#pragma unroll
    for (int t = 0; t < 16; t++) {
        const short* kb = kbh + (size_t)(wv * 256 + t * 16 + l16) * 64;
        short8 b0 = *(const short8*)(kb + quad * 8);
        short8 b1 = *(const short8*)(kb + 32 + quad * 8);
        acc[t] = __builtin_amdgcn_mfma_f32_16x16x32_bf16(aq0, b0, acc[t], 0, 0, 0);
        acc[t] = __builtin_amdgcn_mfma_f32_16x16x32_bf16(aq1, b1, acc[t], 0, 0, 0);
    }
    __syncthreads();   // staging writes visible before sv reads

    // ---- pass 1: row norms of dots and dots*spd (sv from LDS) ----
    float dn[4] = {0.f, 0.f, 0.f, 0.f}, pn[4] = {0.f, 0.f, 0.f, 0.f};
#pragma unroll
    for (int t = 0; t < 16; t++) {
        const int col = wv * 256 + t * 16 + l16;
#pragma unroll
        for (int i = 0; i < 4; i++) {
            float s  = acc[t][i];
            float sv = h2f(sP[quad * 4 + i][col]);
            float ss = s * s;
            dn[i] += ss;
            pn[i] += ss * sv * sv;
        }
    }
#pragma unroll
    for (int m = 1; m < 16; m <<= 1)
#pragma unroll
        for (int i = 0; i < 4; i++) {
            dn[i] += __shfl_xor(dn[i], m, 64);
            pn[i] += __shfl_xor(pn[i], m, 64);
        }
    if (l16 == 0)
#pragma unroll
        for (int i = 0; i < 4; i++) {
            sred[0][wv][quad * 4 + i] = dn[i];
            sred[1][wv][quad * 4 + i] = pn[i];
        }
    __syncthreads();
    if (tid < 16) {
        float d = 0.f, p = 0.f;
        for (int w2 = 0; w2 < 4; w2++) { d += sred[0][w2][tid]; p += sred[1][w2][tid]; }
        ratio_s[tid] = sqrtf(d) / fmaxf(sqrtf(p), 1e-12f);
    }
    __syncthreads();

    // ---- pass 2: logits (overwrite acc) + row max (sv from LDS) ----
    float mx[4] = {-1e30f, -1e30f, -1e30f, -1e30f};
#pragma unroll
    for (int t = 0; t < 16; t++) {
        const int col = wv * 256 + t * 16 + l16;
#pragma unroll
        for (int i = 0; i < 4; i++) {
            float s  = acc[t][i];
            float sv = h2f(sP[quad * 4 + i][col]);
            float l  = s + s * sv * ratio_s[quad * 4 + i];
            acc[t][i] = l;
            mx[i] = fmaxf(mx[i], l);
        }
    }
#pragma unroll
    for (int m = 1; m < 16; m <<= 1)
#pragma unroll
        for (int i = 0; i < 4; i++) mx[i] = fmaxf(mx[i], __shfl_xor(mx[i], m, 64));
    if (l16 == 0)
#pragma unroll
        for (int i = 0; i < 4; i++) sred[0][wv][quad * 4 + i] = mx[i];
    __syncthreads();
    if (tid < 16) {
        float m2 = -1e30f;
        for (int w2 = 0; w2 < 4; w2++) m2 = fmaxf(m2, sred[0][w2][tid]);
        rmax_s[tid] = m2;
    }
    __syncthreads();

    // ---- pass 3: exp (overwrite acc) + row sum ----
    float rs[4] = {0.f, 0.f, 0.f, 0.f};
#pragma unroll
    for (int t = 0; t < 16; t++)
#pragma unroll
        for (int i = 0; i < 4; i++) {
            float p = __expf(acc[t][i] - rmax_s[quad * 4 + i]);
            acc[t][i] = p;
            rs[i] += p;
        }
#pragma unroll
    for (int m = 1; m < 16; m <<= 1)
#pragma unroll
        for (int i = 0; i < 4; i++) rs[i] += __shfl_xor(rs[i], m, 64);
    if (l16 == 0)
#pragma unroll
        for (int i = 0; i < 4; i++) sred[0][wv][quad * 4 + i] = rs[i];
    __syncthreads();
    if (tid < 16) {
        float s = 0.f;
        for (int w2 = 0; w2 < 4; w2++) s += sred[0][w2][tid];
        float hsum = 0.f;
        for (int j = 0; j < 8; j++) hsum += hm[j];
        rinv_s[tid] = (hm[h] * 8.0f / hsum) / s;   // softmax denom + head-mask scale
    }
    __syncthreads();   // all sv reads done (pass2) -> safe to overwrite sP with P

    // ---- P (scaled) -> LDS in row-major, bf16 ----
#pragma unroll
    for (int t = 0; t < 16; t++) {
        const int col = wv * 256 + t * 16 + l16;
#pragma unroll
        for (int i = 0; i < 4; i++)
            sP[quad * 4 + i][col] = f2bf(acc[t][i] * rinv_s[quad * 4 + i]);
    }
    __syncthreads();

    // ---- O = P @ V : wave wv does v-dims [wv*16, wv*16+16), K-loop over 1024
    f32x4 oacc = (f32x4){0.f, 0.f, 0.f, 0.f};
    const short* vb = vt + ((size_t)bh * 64 + wv * 16 + l16) * 1024;
#pragma unroll
    for (int kkk = 0; kkk < 32; kkk++) {
        short8 pa = *(const short8*)&sP[l16][kkk * 32 + quad * 8];
        short8 vf = *(const short8*)(vb + kkk * 32 + quad * 8);
        oacc = __builtin_amdgcn_mfma_f32_16x16x32_bf16(pa, vf, oacc, 0, 0, 0);
    }
#pragma unroll
    for (int i = 0; i < 4; i++)
        o[((size_t)(b * 1024 + q0 + quad * 4 + i)) * 512 + h * 64 + wv * 16 + l16]
            = f2bf(oacc[i]);
}

// ---------------------------------------------------------------------------
// K3: out = O @ W_out + b_out   (M=8192, K=512, N=512), fp32 output
// ---------------------------------------------------------------------------
__global__ __launch_bounds__(256) void out_gemm(
    const short* __restrict__ o, const float* __restrict__ W,
    const float* __restrict__ bias, float* __restrict__ out)
{
    __shared__ short sA[64][40];
    __shared__ short sBt[64][40];

    const int tid  = threadIdx.x;
    const int wv   = tid >> 6, lane = tid & 63;
    const int quad = lane >> 4, l16 = lane & 15;
    const int m0 = blockIdx.x * 64, n0 = blockIdx.y * 64;

    f32x4 acc[4];
#pragma unroll
    for (int i = 0; i < 4; i++) acc[i] = (f32x4){0.f, 0.f, 0.f, 0.f};

    const int ar = tid >> 2, ac = (tid & 3) * 8;
    const int bk = tid >> 3, bn = (tid & 7) * 8;

    for (int ks = 0; ks < 16; ks++) {
        const int k0 = ks * 32;
        short8 av = *(const short8*)(o + (size_t)(m0 + ar) * 512 + k0 + ac);
        const float* wp = W + (size_t)(k0 + bk) * 512 + n0 + bn;
        float4 b0 = *(const float4*)wp;
        float4 b1 = *(const float4*)(wp + 4);

        __syncthreads();
        *(short8*)&sA[ar][ac] = av;
        sBt[bn + 0][bk] = f2bf(b0.x); sBt[bn + 1][bk] = f2bf(b0.y);
        sBt[bn + 2][bk] = f2bf(b0.z); sBt[bn + 3][bk] = f2bf(b0.w);
        sBt[bn + 4][bk] = f2bf(b1.x); sBt[bn + 5][bk] = f2bf(b1.y);
        sBt[bn + 6][bk] = f2bf(b1.z); sBt[bn + 7][bk] = f2bf(b1.w);
        __syncthreads();

        short8 af = *(const short8*)&sA[wv * 16 + l16][quad * 8];
#pragma unroll
        for (int ns = 0; ns < 4; ns++) {
            short8 bf = *(const short8*)&sBt[ns * 16 + l16][quad * 8];
            acc[ns] = __builtin_amdgcn_mfma_f32_16x16x32_bf16(af, bf, acc[ns], 0, 0, 0);
        }
    }

#pragma unroll
    for (int ns = 0; ns < 4; ns++) {
        const int gc = n0 + ns * 16 + l16;
        const float bv = bias[gc];
#pragma unroll
        for (int i = 0; i < 4; i++) {
            const int gm = m0 + wv * 16 + quad * 4 + i;
            out[(size_t)gm * 512 + gc] = acc[ns][i] + bv;
        }
    }
}

// ---------------------------------------------------------------------------
extern "C" void kernel_launch(void* const* d_in, const int* in_sizes, int n_in,
                              void* d_out, int out_size, void* d_ws, size_t ws_size,
                              hipStream_t stream) {
    const float* x    = (const float*)d_in[0];
    const float* spd  = (const float*)d_in[1];
    const float* hm   = (const float*)d_in[2];
    const float* Wqkv = (const float*)d_in[3];
    const float* Wout = (const float*)d_in[4];
    const float* bout = (const float*)d_in[5];
    float* out = (float*)d_out;

    char* ws = (char*)d_ws;
    short* qw  = (short*)(ws);                      // 8 MB  [bh][n][d] bf16 (pre-scaled)
    short* kw  = (short*)(ws + ((size_t)8  << 20)); // 8 MB  [bh][n][d] bf16
    short* vtw = (short*)(ws + ((size_t)16 << 20)); // 8 MB  [bh][d][n] bf16
    short* ow  = (short*)(ws + ((size_t)24 << 20)); // 8 MB  [b][n][h*64+d] bf16

    qkv_gemm<<<dim3(128, 24), 256, 0, stream>>>(x, Wqkv, qw, kw, vtw);
    attn_k  <<<dim3(64, 64),  256, 0, stream>>>(qw, kw, vtw, spd, hm, ow);
    out_gemm<<<dim3(128, 8),  256, 0, stream>>>(ow, Wout, bout, out);
}

// Round 5
// 316.548 us; speedup vs baseline: 1.1093x; 1.1093x over previous
//
#include <hip/hip_runtime.h>
#include <hip/hip_bf16.h>

typedef __attribute__((ext_vector_type(8))) short short8;
typedef __attribute__((ext_vector_type(4))) float f32x4;
typedef __attribute__((ext_vector_type(2))) _Float16 h2;

__device__ inline short f2bf(float f) {
    union { float f; unsigned u; } v; v.f = f;
    unsigned r = v.u + 0x7fffu + ((v.u >> 16) & 1u);
    return (short)(r >> 16);
}

// ---------------------------------------------------------------------------
// K1: qkv = x @ W_qkv   (M=8192, K=512, N=1536), scatter to
//     q[b*8+h][n][d] bf16 (pre-scaled by DH^-0.5), k[..] bf16, vT[bh][d][n]
// ---------------------------------------------------------------------------
__global__ __launch_bounds__(256) void qkv_gemm(
    const float* __restrict__ x, const float* __restrict__ W,
    short* __restrict__ q, short* __restrict__ k, short* __restrict__ vt)
{
    __shared__ short sA[64][40];
    __shared__ short sBt[64][40];

    const int tid  = threadIdx.x;
    const int wv   = tid >> 6, lane = tid & 63;
    const int quad = lane >> 4, l16 = lane & 15;
    const int m0 = blockIdx.x * 64, n0 = blockIdx.y * 64;

    f32x4 acc[4];
#pragma unroll
    for (int i = 0; i < 4; i++) acc[i] = (f32x4){0.f, 0.f, 0.f, 0.f};

    const int ar = tid >> 2, ac = (tid & 3) * 8;
    const int bk = tid >> 3, bn = (tid & 7) * 8;

    for (int ks = 0; ks < 16; ks++) {
        const int k0 = ks * 32;
        const float* xp = x + (size_t)(m0 + ar) * 512 + k0 + ac;
        float4 a0 = *(const float4*)xp;
        float4 a1 = *(const float4*)(xp + 4);
        const float* wp = W + (size_t)(k0 + bk) * 1536 + n0 + bn;
        float4 b0 = *(const float4*)wp;
        float4 b1 = *(const float4*)(wp + 4);

        __syncthreads();
        short8 av = { f2bf(a0.x), f2bf(a0.y), f2bf(a0.z), f2bf(a0.w),
                      f2bf(a1.x), f2bf(a1.y), f2bf(a1.z), f2bf(a1.w) };
        *(short8*)&sA[ar][ac] = av;
        sBt[bn + 0][bk] = f2bf(b0.x); sBt[bn + 1][bk] = f2bf(b0.y);
        sBt[bn + 2][bk] = f2bf(b0.z); sBt[bn + 3][bk] = f2bf(b0.w);
        sBt[bn + 4][bk] = f2bf(b1.x); sBt[bn + 5][bk] = f2bf(b1.y);
        sBt[bn + 6][bk] = f2bf(b1.z); sBt[bn + 7][bk] = f2bf(b1.w);
        __syncthreads();

        short8 af = *(const short8*)&sA[wv * 16 + l16][quad * 8];
#pragma unroll
        for (int ns = 0; ns < 4; ns++) {
            short8 bf = *(const short8*)&sBt[ns * 16 + l16][quad * 8];
            acc[ns] = __builtin_amdgcn_mfma_f32_16x16x32_bf16(af, bf, acc[ns], 0, 0, 0);
        }
    }

#pragma unroll
    for (int ns = 0; ns < 4; ns++) {
        const int gc  = n0 + ns * 16 + l16;
        const int sec = gc >> 9;          // 0=q 1=k 2=v
        const int cc  = gc & 511;
        const int h = cc >> 6, d = cc & 63;
#pragma unroll
        for (int i = 0; i < 4; i++) {
            const int gm = m0 + wv * 16 + quad * 4 + i;
            const int b = gm >> 10, n = gm & 1023;
            const int bh = b * 8 + h;
            if (sec == 0)      q[((size_t)(bh * 1024 + n)) * 64 + d] = f2bf(acc[ns][i] * 0.125f);
            else if (sec == 1) k[((size_t)(bh * 1024 + n)) * 64 + d] = f2bf(acc[ns][i]);
            else               vt[((size_t)(bh * 64 + d)) * 1024 + n] = f2bf(acc[ns][i]);
        }
    }
}

// ---------------------------------------------------------------------------
// K2: attention. One block = one (b,h) x 16 query rows. 4 waves x 256 cols.
// Score stripe in 64 acc regs/lane (ALL acc loops fully unrolled — runtime
// index demotes to scratch, R1 lesson). spd loaded ONCE into registers
// (fp16-packed, 32 VGPRs), chunk-interleaved with the QK MFMA halves.
// 4 barriers total; per-row reduction results recomputed per-lane from
// wave partials (no broadcast round-trips).
// ---------------------------------------------------------------------------
__global__ __launch_bounds__(256, 3) void attn_k(
    const short* __restrict__ q, const short* __restrict__ kk,
    const short* __restrict__ vt, const float* __restrict__ spd,
    const float* __restrict__ hm, short* __restrict__ o)
{
    __shared__ short sP[16][1032];     // 33 KB: bf16 P for the PV phase
    __shared__ float sred[4][4][16];   // slots: 0=dn 1=pn 2=max 3=sum

    const int tid  = threadIdx.x;
    const int wv   = tid >> 6, lane = tid & 63;
    const int quad = lane >> 4, l16 = lane & 15;
    const int qt = blockIdx.x, bh = blockIdx.y;
    const int b = bh >> 3, h = bh & 7;
    const int q0 = qt * 16;

    // Q fragments (A-layout): m = l16, k = quad*8+j (+32 for second step)
    const short* qb = q + ((size_t)bh * 1024 + q0 + l16) * 64;
    short8 aq0 = *(const short8*)(qb + quad * 8);
    short8 aq1 = *(const short8*)(qb + 32 + quad * 8);

    f32x4 acc[16];
#pragma unroll
    for (int t = 0; t < 16; t++) acc[t] = (f32x4){0.f, 0.f, 0.f, 0.f};

    const short* kbh = kk + (size_t)bh * 1024 * 64;
    // spd base for this lane's 4 rows (quad*4 .. quad*4+3)
    const float* spdb = spd + ((size_t)b * 1024 + q0 + quad * 4) * 1024;

    h2 svp[16][2];   // fp16-packed spd values, 2 rows per reg

    // ---- chunk A spd loads (32 dwords in flight) ----
    float svfA[8][4];
#pragma unroll
    for (int t = 0; t < 8; t++) {
        const float* sp = spdb + wv * 256 + t * 16 + l16;
        svfA[t][0] = sp[0];    svfA[t][1] = sp[1024];
        svfA[t][2] = sp[2048]; svfA[t][3] = sp[3072];
    }
    // ---- QK half 1 ----
#pragma unroll
    for (int t = 0; t < 8; t++) {
        const short* kb = kbh + (size_t)(wv * 256 + t * 16 + l16) * 64;
        short8 b0 = *(const short8*)(kb + quad * 8);
        short8 b1 = *(const short8*)(kb + 32 + quad * 8);
        acc[t] = __builtin_amdgcn_mfma_f32_16x16x32_bf16(aq0, b0, acc[t], 0, 0, 0);
        acc[t] = __builtin_amdgcn_mfma_f32_16x16x32_bf16(aq1, b1, acc[t], 0, 0, 0);
    }
    // ---- pack A (frees 32 regs) ----
#pragma unroll
    for (int t = 0; t < 8; t++) {
        svp[t][0] = (h2){(_Float16)svfA[t][0], (_Float16)svfA[t][1]};
        svp[t][1] = (h2){(_Float16)svfA[t][2], (_Float16)svfA[t][3]};
    }
    // ---- chunk B spd loads ----
    float svfB[8][4];
#pragma unroll
    for (int t = 0; t < 8; t++) {
        const float* sp = spdb + wv * 256 + (t + 8) * 16 + l16;
        svfB[t][0] = sp[0];    svfB[t][1] = sp[1024];
        svfB[t][2] = sp[2048]; svfB[t][3] = sp[3072];
    }
    // ---- QK half 2 ----
#pragma unroll
    for (int t = 8; t < 16; t++) {
        const short* kb = kbh + (size_t)(wv * 256 + t * 16 + l16) * 64;
        short8 b0 = *(const short8*)(kb + quad * 8);
        short8 b1 = *(const short8*)(kb + 32 + quad * 8);
        acc[t] = __builtin_amdgcn_mfma_f32_16x16x32_bf16(aq0, b0, acc[t], 0, 0, 0);
        acc[t] = __builtin_amdgcn_mfma_f32_16x16x32_bf16(aq1, b1, acc[t], 0, 0, 0);
    }
    // ---- pack B ----
#pragma unroll
    for (int t = 0; t < 8; t++) {
        svp[t + 8][0] = (h2){(_Float16)svfB[t][0], (_Float16)svfB[t][1]};
        svp[t + 8][1] = (h2){(_Float16)svfB[t][2], (_Float16)svfB[t][3]};
    }

    // ---- pass 1: row norms of dots and dots*spd ----
    float dn[4] = {0.f, 0.f, 0.f, 0.f}, pn[4] = {0.f, 0.f, 0.f, 0.f};
#pragma unroll
    for (int t = 0; t < 16; t++)
#pragma unroll
        for (int i = 0; i < 4; i++) {
            float s  = acc[t][i];
            float sv = (float)svp[t][i >> 1][i & 1];
            float ps = s * sv;
            dn[i] += s * s;
            pn[i] += ps * ps;
        }
#pragma unroll
    for (int m = 1; m < 16; m <<= 1)
#pragma unroll
        for (int i = 0; i < 4; i++) {
            dn[i] += __shfl_xor(dn[i], m, 64);
            pn[i] += __shfl_xor(pn[i], m, 64);
        }
    if (l16 == 0)
#pragma unroll
        for (int i = 0; i < 4; i++) {
            sred[0][wv][quad * 4 + i] = dn[i];
            sred[1][wv][quad * 4 + i] = pn[i];
        }
    __syncthreads();                                    // barrier 1
    float ratio[4];
#pragma unroll
    for (int i = 0; i < 4; i++) {
        const int row = quad * 4 + i;
        float d = sred[0][0][row] + sred[0][1][row] + sred[0][2][row] + sred[0][3][row];
        float p = sred[1][0][row] + sred[1][1][row] + sred[1][2][row] + sred[1][3][row];
        ratio[i] = sqrtf(d) / fmaxf(sqrtf(p), 1e-12f);
    }

    // ---- pass 2: logits (overwrite acc) + row max ----
    float mx[4] = {-1e30f, -1e30f, -1e30f, -1e30f};
#pragma unroll
    for (int t = 0; t < 16; t++)
#pragma unroll
        for (int i = 0; i < 4; i++) {
            float s  = acc[t][i];
            float sv = (float)svp[t][i >> 1][i & 1];
            float l  = s * fmaf(sv, ratio[i], 1.0f);
            acc[t][i] = l;
            mx[i] = fmaxf(mx[i], l);
        }
#pragma unroll
    for (int m = 1; m < 16; m <<= 1)
#pragma unroll
        for (int i = 0; i < 4; i++) mx[i] = fmaxf(mx[i], __shfl_xor(mx[i], m, 64));
    if (l16 == 0)
#pragma unroll
        for (int i = 0; i < 4; i++) sred[2][wv][quad * 4 + i] = mx[i];
    __syncthreads();                                    // barrier 2
    float mrow[4];
#pragma unroll
    for (int i = 0; i < 4; i++) {
        const int row = quad * 4 + i;
        mrow[i] = fmaxf(fmaxf(sred[2][0][row], sred[2][1][row]),
                        fmaxf(sred[2][2][row], sred[2][3][row]));
    }

    // ---- pass 3: exp (overwrite acc) + row sum ----
    float rs[4] = {0.f, 0.f, 0.f, 0.f};
#pragma unroll
    for (int t = 0; t < 16; t++)
#pragma unroll
        for (int i = 0; i < 4; i++) {
            float p = __expf(acc[t][i] - mrow[i]);
            acc[t][i] = p;
            rs[i] += p;
        }
#pragma unroll
    for (int m = 1; m < 16; m <<= 1)
#pragma unroll
        for (int i = 0; i < 4; i++) rs[i] += __shfl_xor(rs[i], m, 64);
    if (l16 == 0)
#pragma unroll
        for (int i = 0; i < 4; i++) sred[3][wv][quad * 4 + i] = rs[i];
    __syncthreads();                                    // barrier 3
    const float hsum = hm[0] + hm[1] + hm[2] + hm[3] + hm[4] + hm[5] + hm[6] + hm[7];
    const float hscale = hm[h] * 8.0f / hsum;
    float rinv[4];
#pragma unroll
    for (int i = 0; i < 4; i++) {
        const int row = quad * 4 + i;
        float s = sred[3][0][row] + sred[3][1][row] + sred[3][2][row] + sred[3][3][row];
        rinv[i] = hscale / s;
    }

    // ---- P (scaled) -> LDS in row-major, bf16 ----
#pragma unroll
    for (int t = 0; t < 16; t++) {
        const int col = wv * 256 + t * 16 + l16;
#pragma unroll
        for (int i = 0; i < 4; i++)
            sP[quad * 4 + i][col] = f2bf(acc[t][i] * rinv[i]);
    }
    __syncthreads();                                    // barrier 4

    // ---- O = P @ V : wave wv does v-dims [wv*16, wv*16+16), K-loop over 1024
    f32x4 oacc = (f32x4){0.f, 0.f, 0.f, 0.f};
    const short* vb = vt + ((size_t)bh * 64 + wv * 16 + l16) * 1024;
#pragma unroll
    for (int kkk = 0; kkk < 32; kkk++) {
        short8 pa = *(const short8*)&sP[l16][kkk * 32 + quad * 8];
        short8 vf = *(const short8*)(vb + kkk * 32 + quad * 8);
        oacc = __builtin_amdgcn_mfma_f32_16x16x32_bf16(pa, vf, oacc, 0, 0, 0);
    }
#pragma unroll
    for (int i = 0; i < 4; i++)
        o[((size_t)(b * 1024 + q0 + quad * 4 + i)) * 512 + h * 64 + wv * 16 + l16]
            = f2bf(oacc[i]);
}

// ---------------------------------------------------------------------------
// K3: out = O @ W_out + b_out   (M=8192, K=512, N=512), fp32 output
// ---------------------------------------------------------------------------
__global__ __launch_bounds__(256) void out_gemm(
    const short* __restrict__ o, const float* __restrict__ W,
    const float* __restrict__ bias, float* __restrict__ out)
{
    __shared__ short sA[64][40];
    __shared__ short sBt[64][40];

    const int tid  = threadIdx.x;
    const int wv   = tid >> 6, lane = tid & 63;
    const int quad = lane >> 4, l16 = lane & 15;
    const int m0 = blockIdx.x * 64, n0 = blockIdx.y * 64;

    f32x4 acc[4];
#pragma unroll
    for (int i = 0; i < 4; i++) acc[i] = (f32x4){0.f, 0.f, 0.f, 0.f};

    const int ar = tid >> 2, ac = (tid & 3) * 8;
    const int bk = tid >> 3, bn = (tid & 7) * 8;

    for (int ks = 0; ks < 16; ks++) {
        const int k0 = ks * 32;
        short8 av = *(const short8*)(o + (size_t)(m0 + ar) * 512 + k0 + ac);
        const float* wp = W + (size_t)(k0 + bk) * 512 + n0 + bn;
        float4 b0 = *(const float4*)wp;
        float4 b1 = *(const float4*)(wp + 4);

        __syncthreads();
        *(short8*)&sA[ar][ac] = av;
        sBt[bn + 0][bk] = f2bf(b0.x); sBt[bn + 1][bk] = f2bf(b0.y);
        sBt[bn + 2][bk] = f2bf(b0.z); sBt[bn + 3][bk] = f2bf(b0.w);
        sBt[bn + 4][bk] = f2bf(b1.x); sBt[bn + 5][bk] = f2bf(b1.y);
        sBt[bn + 6][bk] = f2bf(b1.z); sBt[bn + 7][bk] = f2bf(b1.w);
        __syncthreads();

        short8 af = *(const short8*)&sA[wv * 16 + l16][quad * 8];
#pragma unroll
        for (int ns = 0; ns < 4; ns++) {
            short8 bf = *(const short8*)&sBt[ns * 16 + l16][quad * 8];
            acc[ns] = __builtin_amdgcn_mfma_f32_16x16x32_bf16(af, bf, acc[ns], 0, 0, 0);
        }
    }

#pragma unroll
    for (int ns = 0; ns < 4; ns++) {
        const int gc = n0 + ns * 16 + l16;
        const float bv = bias[gc];
#pragma unroll
        for (int i = 0; i < 4; i++) {
            const int gm = m0 + wv * 16 + quad * 4 + i;
            out[(size_t)gm * 512 + gc] = acc[ns][i] + bv;
        }
    }
}

// ---------------------------------------------------------------------------
extern "C" void kernel_launch(void* const* d_in, const int* in_sizes, int n_in,
                              void* d_out, int out_size, void* d_ws, size_t ws_size,
                              hipStream_t stream) {
    const float* x    = (const float*)d_in[0];
    const float* spd  = (const float*)d_in[1];
    const float* hm   = (const float*)d_in[2];
    const float* Wqkv = (const float*)d_in[3];
    const float* Wout = (const float*)d_in[4];
    const float* bout = (const float*)d_in[5];
    float* out = (float*)d_out;

    char* ws = (char*)d_ws;
    short* qw  = (short*)(ws);                      // 8 MB  [bh][n][d] bf16 (pre-scaled)
    short* kw  = (short*)(ws + ((size_t)8  << 20)); // 8 MB  [bh][n][d] bf16
    short* vtw = (short*)(ws + ((size_t)16 << 20)); // 8 MB  [bh][d][n] bf16
    short* ow  = (short*)(ws + ((size_t)24 << 20)); // 8 MB  [b][n][h*64+d] bf16

    qkv_gemm<<<dim3(128, 24), 256, 0, stream>>>(x, Wqkv, qw, kw, vtw);
    attn_k  <<<dim3(64, 64),  256, 0, stream>>>(qw, kw, vtw, spd, hm, ow);
    out_gemm<<<dim3(128, 8),  256, 0, stream>>>(ow, Wout, bout, out);
}

// Round 6
// 276.001 us; speedup vs baseline: 1.2722x; 1.1469x over previous
//
#include <hip/hip_runtime.h>
#include <hip/hip_bf16.h>

typedef __attribute__((ext_vector_type(8))) short short8;
typedef __attribute__((ext_vector_type(4))) short s16x4;
typedef __attribute__((ext_vector_type(4))) float f32x4;
typedef __attribute__((ext_vector_type(2))) _Float16 h2;

typedef const __attribute__((address_space(1))) unsigned* gp1;
typedef __attribute__((address_space(3))) unsigned* lp3;

__device__ inline short f2bf(float f) {
    union { float f; unsigned u; } v; v.f = f;
    unsigned r = v.u + 0x7fffu + ((v.u >> 16) & 1u);
    return (short)(r >> 16);
}

// ---------------------------------------------------------------------------
// P0: fp32 -> bf16 flat convert (x)
// ---------------------------------------------------------------------------
__global__ __launch_bounds__(256) void cvt_bf16(
    const float* __restrict__ src, short* __restrict__ dst, int n4)
{
    int i = blockIdx.x * 256 + threadIdx.x;
    if (i < n4) {
        float4 v = ((const float4*)src)[i];
        s16x4 o = { f2bf(v.x), f2bf(v.y), f2bf(v.z), f2bf(v.w) };
        ((s16x4*)dst)[i] = o;
    }
}

// ---------------------------------------------------------------------------
// P1: W[K][N] fp32 -> W^T[N][K] bf16 (64x64 LDS tile transpose)
// ---------------------------------------------------------------------------
__global__ __launch_bounds__(256) void tr_w(
    const float* __restrict__ src, short* __restrict__ dst, int K, int N)
{
    __shared__ float t[64][65];
    const int k0 = blockIdx.x * 64, n0 = blockIdx.y * 64;
    const int r = threadIdx.x >> 4, c4 = (threadIdx.x & 15) * 4;
#pragma unroll
    for (int j = 0; j < 4; j++) {
        float4 v = *(const float4*)(src + (size_t)(k0 + r + 16 * j) * N + n0 + c4);
        t[r + 16 * j][c4 + 0] = v.x; t[r + 16 * j][c4 + 1] = v.y;
        t[r + 16 * j][c4 + 2] = v.z; t[r + 16 * j][c4 + 3] = v.w;
    }
    __syncthreads();
#pragma unroll
    for (int j = 0; j < 4; j++) {
        const int n = r + 16 * j;
        s16x4 o = { f2bf(t[c4 + 0][n]), f2bf(t[c4 + 1][n]),
                    f2bf(t[c4 + 2][n]), f2bf(t[c4 + 3][n]) };
        *(s16x4*)(dst + (size_t)(n0 + n) * K + k0 + c4) = o;
    }
}

// ---------------------------------------------------------------------------
// K1: qkv = xb @ WqT^T  (M=8192, K=512, N=1536), m97-style 128x128 tile,
//     BK=32, global_load_lds 16B staging, scatter epilogue to q/k/vT.
// ---------------------------------------------------------------------------
__global__ __launch_bounds__(256) void qkv_gemm(
    const short* __restrict__ A, const short* __restrict__ BT,
    short* __restrict__ q, short* __restrict__ k, short* __restrict__ vt)
{
    __shared__ short sA[128][32];   // NO padding: global_load_lds needs dense
    __shared__ short sB[128][32];

    const int tid  = threadIdx.x;
    const int wv   = tid >> 6, lane = tid & 63;
    const int quad = lane >> 4, l16 = lane & 15;
    const int wr = wv >> 1, wc = wv & 1;
    const int m0 = blockIdx.x * 128, n0 = blockIdx.y * 128;

    f32x4 acc[4][4];
#pragma unroll
    for (int i = 0; i < 4; i++)
#pragma unroll
        for (int j = 0; j < 4; j++) acc[i][j] = (f32x4){0.f, 0.f, 0.f, 0.f};

    // staging: wave wv covers rows wv*32 + j*16 + (lane>>2), col chunk (lane&3)*8
    const short* a_src = A  + (size_t)(m0 + wv * 32 + (lane >> 2)) * 512 + (lane & 3) * 8;
    const short* b_src = BT + (size_t)(n0 + wv * 32 + (lane >> 2)) * 512 + (lane & 3) * 8;
    char* a_dst = (char*)sA + wv * 2048;
    char* b_dst = (char*)sB + wv * 2048;

    for (int ks = 0; ks < 16; ks++) {
        __syncthreads();
        const short* ap = a_src + ks * 32;
        const short* bp = b_src + ks * 32;
        __builtin_amdgcn_global_load_lds((gp1)(ap),            (lp3)(a_dst),        16, 0, 0);
        __builtin_amdgcn_global_load_lds((gp1)(ap + 16 * 512), (lp3)(a_dst + 1024), 16, 0, 0);
        __builtin_amdgcn_global_load_lds((gp1)(bp),            (lp3)(b_dst),        16, 0, 0);
        __builtin_amdgcn_global_load_lds((gp1)(bp + 16 * 512), (lp3)(b_dst + 1024), 16, 0, 0);
        __syncthreads();

        short8 af[4], bf[4];
#pragma unroll
        for (int f = 0; f < 4; f++) {
            af[f] = *(const short8*)&sA[wr * 64 + f * 16 + l16][quad * 8];
            bf[f] = *(const short8*)&sB[wc * 64 + f * 16 + l16][quad * 8];
        }
#pragma unroll
        for (int fm = 0; fm < 4; fm++)
#pragma unroll
            for (int fn = 0; fn < 4; fn++)
                acc[fm][fn] = __builtin_amdgcn_mfma_f32_16x16x32_bf16(
                    af[fm], bf[fn], acc[fm][fn], 0, 0, 0);
    }

    // epilogue: section is uniform per block (n0 multiple of 128, sections 512-aligned)
    const int sec = n0 >> 9;   // 0=q 1=k 2=v
#pragma unroll
    for (int fn = 0; fn < 4; fn++) {
        const int gc = n0 + wc * 64 + fn * 16 + l16;
        const int cc = gc & 511;
        const int h = cc >> 6, d = cc & 63;
#pragma unroll
        for (int fm = 0; fm < 4; fm++)
#pragma unroll
            for (int i = 0; i < 4; i++) {
                const int gm = m0 + wr * 64 + fm * 16 + quad * 4 + i;
                const int b = gm >> 10, n = gm & 1023;
                const int bh = b * 8 + h;
                if (sec == 0)      q[((size_t)(bh * 1024 + n)) * 64 + d] = f2bf(acc[fm][fn][i] * 0.125f);
                else if (sec == 1) k[((size_t)(bh * 1024 + n)) * 64 + d] = f2bf(acc[fm][fn][i]);
                else               vt[((size_t)(bh * 64 + d)) * 1024 + n] = f2bf(acc[fm][fn][i]);
            }
    }
}

// ---------------------------------------------------------------------------
// K2: attention (unchanged from R5). One block = one (b,h) x 16 query rows.
// ---------------------------------------------------------------------------
__global__ __launch_bounds__(256, 3) void attn_k(
    const short* __restrict__ q, const short* __restrict__ kk,
    const short* __restrict__ vt, const float* __restrict__ spd,
    const float* __restrict__ hm, short* __restrict__ o)
{
    __shared__ short sP[16][1032];
    __shared__ float sred[4][4][16];

    const int tid  = threadIdx.x;
    const int wv   = tid >> 6, lane = tid & 63;
    const int quad = lane >> 4, l16 = lane & 15;
    const int qt = blockIdx.x, bh = blockIdx.y;
    const int b = bh >> 3, h = bh & 7;
    const int q0 = qt * 16;

    const short* qb = q + ((size_t)bh * 1024 + q0 + l16) * 64;
    short8 aq0 = *(const short8*)(qb + quad * 8);
    short8 aq1 = *(const short8*)(qb + 32 + quad * 8);

    f32x4 acc[16];
#pragma unroll
    for (int t = 0; t < 16; t++) acc[t] = (f32x4){0.f, 0.f, 0.f, 0.f};

    const short* kbh = kk + (size_t)bh * 1024 * 64;
    const float* spdb = spd + ((size_t)b * 1024 + q0 + quad * 4) * 1024;

    h2 svp[16][2];

    float svfA[8][4];
#pragma unroll
    for (int t = 0; t < 8; t++) {
        const float* sp = spdb + wv * 256 + t * 16 + l16;
        svfA[t][0] = sp[0];    svfA[t][1] = sp[1024];
        svfA[t][2] = sp[2048]; svfA[t][3] = sp[3072];
    }
#pragma unroll
    for (int t = 0; t < 8; t++) {
        const short* kb = kbh + (size_t)(wv * 256 + t * 16 + l16) * 64;
        short8 b0 = *(const short8*)(kb + quad * 8);
        short8 b1 = *(const short8*)(kb + 32 + quad * 8);
        acc[t] = __builtin_amdgcn_mfma_f32_16x16x32_bf16(aq0, b0, acc[t], 0, 0, 0);
        acc[t] = __builtin_amdgcn_mfma_f32_16x16x32_bf16(aq1, b1, acc[t], 0, 0, 0);
    }
#pragma unroll
    for (int t = 0; t < 8; t++) {
        svp[t][0] = (h2){(_Float16)svfA[t][0], (_Float16)svfA[t][1]};
        svp[t][1] = (h2){(_Float16)svfA[t][2], (_Float16)svfA[t][3]};
    }
    float svfB[8][4];
#pragma unroll
    for (int t = 0; t < 8; t++) {
        const float* sp = spdb + wv * 256 + (t + 8) * 16 + l16;
        svfB[t][0] = sp[0];    svfB[t][1] = sp[1024];
        svfB[t][2] = sp[2048]; svfB[t][3] = sp[3072];
    }
#pragma unroll
    for (int t = 8; t < 16; t++) {
        const short* kb = kbh + (size_t)(wv * 256 + t * 16 + l16) * 64;
        short8 b0 = *(const short8*)(kb + quad * 8);
        short8 b1 = *(const short8*)(kb + 32 + quad * 8);
        acc[t] = __builtin_amdgcn_mfma_f32_16x16x32_bf16(aq0, b0, acc[t], 0, 0, 0);
        acc[t] = __builtin_amdgcn_mfma_f32_16x16x32_bf16(aq1, b1, acc[t], 0, 0, 0);
    }
#pragma unroll
    for (int t = 0; t < 8; t++) {
        svp[t + 8][0] = (h2){(_Float16)svfB[t][0], (_Float16)svfB[t][1]};
        svp[t + 8][1] = (h2){(_Float16)svfB[t][2], (_Float16)svfB[t][3]};
    }

    float dn[4] = {0.f, 0.f, 0.f, 0.f}, pn[4] = {0.f, 0.f, 0.f, 0.f};
#pragma unroll
    for (int t = 0; t < 16; t++)
#pragma unroll
        for (int i = 0; i < 4; i++) {
            float s  = acc[t][i];
            float sv = (float)svp[t][i >> 1][i & 1];
            float ps = s * sv;
            dn[i] += s * s;
            pn[i] += ps * ps;
        }
#pragma unroll
    for (int m = 1; m < 16; m <<= 1)
#pragma unroll
        for (int i = 0; i < 4; i++) {
            dn[i] += __shfl_xor(dn[i], m, 64);
            pn[i] += __shfl_xor(pn[i], m, 64);
        }
    if (l16 == 0)
#pragma unroll
        for (int i = 0; i < 4; i++) {
            sred[0][wv][quad * 4 + i] = dn[i];
            sred[1][wv][quad * 4 + i] = pn[i];
        }
    __syncthreads();
    float ratio[4];
#pragma unroll
    for (int i = 0; i < 4; i++) {
        const int row = quad * 4 + i;
        float d = sred[0][0][row] + sred[0][1][row] + sred[0][2][row] + sred[0][3][row];
        float p = sred[1][0][row] + sred[1][1][row] + sred[1][2][row] + sred[1][3][row];
        ratio[i] = sqrtf(d) / fmaxf(sqrtf(p), 1e-12f);
    }

    float mx[4] = {-1e30f, -1e30f, -1e30f, -1e30f};
#pragma unroll
    for (int t = 0; t < 16; t++)
#pragma unroll
        for (int i = 0; i < 4; i++) {
            float s  = acc[t][i];
            float sv = (float)svp[t][i >> 1][i & 1];
            float l  = s * fmaf(sv, ratio[i], 1.0f);
            acc[t][i] = l;
            mx[i] = fmaxf(mx[i], l);
        }
#pragma unroll
    for (int m = 1; m < 16; m <<= 1)
#pragma unroll
        for (int i = 0; i < 4; i++) mx[i] = fmaxf(mx[i], __shfl_xor(mx[i], m, 64));
    if (l16 == 0)
#pragma unroll
        for (int i = 0; i < 4; i++) sred[2][wv][quad * 4 + i] = mx[i];
    __syncthreads();
    float mrow[4];
#pragma unroll
    for (int i = 0; i < 4; i++) {
        const int row = quad * 4 + i;
        mrow[i] = fmaxf(fmaxf(sred[2][0][row], sred[2][1][row]),
                        fmaxf(sred[2][2][row], sred[2][3][row]));
    }

    float rs[4] = {0.f, 0.f, 0.f, 0.f};
#pragma unroll
    for (int t = 0; t < 16; t++)
#pragma unroll
        for (int i = 0; i < 4; i++) {
            float p = __expf(acc[t][i] - mrow[i]);
            acc[t][i] = p;
            rs[i] += p;
        }
#pragma unroll
    for (int m = 1; m < 16; m <<= 1)
#pragma unroll
        for (int i = 0; i < 4; i++) rs[i] += __shfl_xor(rs[i], m, 64);
    if (l16 == 0)
#pragma unroll
        for (int i = 0; i < 4; i++) sred[3][wv][quad * 4 + i] = rs[i];
    __syncthreads();
    const float hsum = hm[0] + hm[1] + hm[2] + hm[3] + hm[4] + hm[5] + hm[6] + hm[7];
    const float hscale = hm[h] * 8.0f / hsum;
    float rinv[4];
#pragma unroll
    for (int i = 0; i < 4; i++) {
        const int row = quad * 4 + i;
        float s = sred[3][0][row] + sred[3][1][row] + sred[3][2][row] + sred[3][3][row];
        rinv[i] = hscale / s;
    }

#pragma unroll
    for (int t = 0; t < 16; t++) {
        const int col = wv * 256 + t * 16 + l16;
#pragma unroll
        for (int i = 0; i < 4; i++)
            sP[quad * 4 + i][col] = f2bf(acc[t][i] * rinv[i]);
    }
    __syncthreads();

    f32x4 oacc = (f32x4){0.f, 0.f, 0.f, 0.f};
    const short* vb = vt + ((size_t)bh * 64 + wv * 16 + l16) * 1024;
#pragma unroll
    for (int kkk = 0; kkk < 32; kkk++) {
        short8 pa = *(const short8*)&sP[l16][kkk * 32 + quad * 8];
        short8 vf = *(const short8*)(vb + kkk * 32 + quad * 8);
        oacc = __builtin_amdgcn_mfma_f32_16x16x32_bf16(pa, vf, oacc, 0, 0, 0);
    }
#pragma unroll
    for (int i = 0; i < 4; i++)
        o[((size_t)(b * 1024 + q0 + quad * 4 + i)) * 512 + h * 64 + wv * 16 + l16]
            = f2bf(oacc[i]);
}

// ---------------------------------------------------------------------------
// K3: out = O @ WoT^T + b_out  (M=8192, K=512, N=512), 128x128 tile, fp32 out
// ---------------------------------------------------------------------------
__global__ __launch_bounds__(256) void out_gemm(
    const short* __restrict__ A, const short* __restrict__ BT,
    const float* __restrict__ bias, float* __restrict__ out)
{
    __shared__ short sA[128][32];
    __shared__ short sB[128][32];

    const int tid  = threadIdx.x;
    const int wv   = tid >> 6, lane = tid & 63;
    const int quad = lane >> 4, l16 = lane & 15;
    const int wr = wv >> 1, wc = wv & 1;
    const int m0 = blockIdx.x * 128, n0 = blockIdx.y * 128;

    f32x4 acc[4][4];
#pragma unroll
    for (int i = 0; i < 4; i++)
#pragma unroll
        for (int j = 0; j < 4; j++) acc[i][j] = (f32x4){0.f, 0.f, 0.f, 0.f};

    const short* a_src = A  + (size_t)(m0 + wv * 32 + (lane >> 2)) * 512 + (lane & 3) * 8;
    const short* b_src = BT + (size_t)(n0 + wv * 32 + (lane >> 2)) * 512 + (lane & 3) * 8;
    char* a_dst = (char*)sA + wv * 2048;
    char* b_dst = (char*)sB + wv * 2048;

    for (int ks = 0; ks < 16; ks++) {
        __syncthreads();
        const short* ap = a_src + ks * 32;
        const short* bp = b_src + ks * 32;
        __builtin_amdgcn_global_load_lds((gp1)(ap),            (lp3)(a_dst),        16, 0, 0);
        __builtin_amdgcn_global_load_lds((gp1)(ap + 16 * 512), (lp3)(a_dst + 1024), 16, 0, 0);
        __builtin_amdgcn_global_load_lds((gp1)(bp),            (lp3)(b_dst),        16, 0, 0);
        __builtin_amdgcn_global_load_lds((gp1)(bp + 16 * 512), (lp3)(b_dst + 1024), 16, 0, 0);
        __syncthreads();

        short8 af[4], bf[4];
#pragma unroll
        for (int f = 0; f < 4; f++) {
            af[f] = *(const short8*)&sA[wr * 64 + f * 16 + l16][quad * 8];
            bf[f] = *(const short8*)&sB[wc * 64 + f * 16 + l16][quad * 8];
        }
#pragma unroll
        for (int fm = 0; fm < 4; fm++)
#pragma unroll
            for (int fn = 0; fn < 4; fn++)
                acc[fm][fn] = __builtin_amdgcn_mfma_f32_16x16x32_bf16(
                    af[fm], bf[fn], acc[fm][fn], 0, 0, 0);
    }

#pragma unroll
    for (int fn = 0; fn < 4; fn++) {
        const int gc = n0 + wc * 64 + fn * 16 + l16;
        const float bv = bias[gc];
#pragma unroll
        for (int fm = 0; fm < 4; fm++)
#pragma unroll
            for (int i = 0; i < 4; i++) {
                const int gm = m0 + wr * 64 + fm * 16 + quad * 4 + i;
                out[(size_t)gm * 512 + gc] = acc[fm][fn][i] + bv;
            }
    }
}

// ---------------------------------------------------------------------------
extern "C" void kernel_launch(void* const* d_in, const int* in_sizes, int n_in,
                              void* d_out, int out_size, void* d_ws, size_t ws_size,
                              hipStream_t stream) {
    const float* x    = (const float*)d_in[0];
    const float* spd  = (const float*)d_in[1];
    const float* hm   = (const float*)d_in[2];
    const float* Wqkv = (const float*)d_in[3];
    const float* Wout = (const float*)d_in[4];
    const float* bout = (const float*)d_in[5];
    float* out = (float*)d_out;

    char* ws = (char*)d_ws;
    short* qw  = (short*)(ws);                      // 8 MB  [bh][n][d] bf16 (pre-scaled)
    short* kw  = (short*)(ws + ((size_t)8  << 20)); // 8 MB  [bh][n][d] bf16
    short* vtw = (short*)(ws + ((size_t)16 << 20)); // 8 MB  [bh][d][n] bf16
    short* ow  = (short*)(ws + ((size_t)24 << 20)); // 8 MB  [b][n][h*64+d] bf16
    short* xb  = (short*)(ws + ((size_t)32 << 20)); // 8 MB  x bf16 [8192][512]
    short* wqT = (short*)(ws + ((size_t)40 << 20)); // 1.5MB Wqkv^T bf16 [1536][512]
    short* woT = (short*)(ws + ((size_t)42 << 20)); // 0.5MB Wout^T bf16 [512][512]

    cvt_bf16<<<4096, 256, 0, stream>>>(x, xb, 8192 * 512 / 4);
    tr_w    <<<dim3(8, 24), 256, 0, stream>>>(Wqkv, wqT, 512, 1536);
    tr_w    <<<dim3(8, 8),  256, 0, stream>>>(Wout, woT, 512, 512);

    qkv_gemm<<<dim3(64, 12), 256, 0, stream>>>(xb, wqT, qw, kw, vtw);
    attn_k  <<<dim3(64, 64), 256, 0, stream>>>(qw, kw, vtw, spd, hm, ow);
    out_gemm<<<dim3(64, 4),  256, 0, stream>>>(ow, woT, bout, out);
}